// Round 2
// baseline (335.490 us; speedup 1.0000x reference)
//
#include <hip/hip_runtime.h>

#define B_ 128
#define S_ 512
#define H_ 256
#define M_ (B_*S_)

typedef __attribute__((ext_vector_type(4))) float f32x4;
typedef __attribute__((ext_vector_type(8))) short s16x8;
typedef __attribute__((ext_vector_type(4))) unsigned short u16x4;
typedef unsigned short ushort_t;

typedef __attribute__((address_space(1))) void as1_void;
typedef __attribute__((address_space(3))) void as3_void;

__device__ __forceinline__ unsigned short f2h(float f) {
  _Float16 h = (_Float16)f;              // v_cvt_f16_f32, RTNE
  return __builtin_bit_cast(unsigned short, h);
}

__device__ __forceinline__ f32x4 mfma16(s16x8 a, s16x8 b, f32x4 c) {
  // D tied to C: in-place accumulate; fp16 variant (4x lower quant error than bf16)
  asm("v_mfma_f32_16x16x32_f16 %0, %1, %2, %0" : "+v"(c) : "v"(a), "v"(b));
  return c;
}

__device__ __forceinline__ void cp16(const void* g, void* l) {
  __builtin_amdgcn_global_load_lds((as1_void*)g, (as3_void*)l, 16, 0, 0);
}

__global__ void k_cvt_f16(const float* __restrict__ in, ushort_t* __restrict__ out, int n8) {
  int i = blockIdx.x * blockDim.x + threadIdx.x;
  if (i >= n8) return;
  const float* p = in + (size_t)i * 8;
  f32x4 a = *(const f32x4*)p;
  f32x4 b = *(const f32x4*)(p + 4);
  s16x8 o;
  o[0]=(short)f2h(a[0]); o[1]=(short)f2h(a[1]); o[2]=(short)f2h(a[2]); o[3]=(short)f2h(a[3]);
  o[4]=(short)f2h(b[0]); o[5]=(short)f2h(b[1]); o[6]=(short)f2h(b[2]); o[7]=(short)f2h(b[3]);
  *(s16x8*)(out + (size_t)i * 8) = o;
}

// K1: h_catT[b][n][j] = sum_k hid_h[b*512+j][k] * Wcat[n][k] + bcat[n]   (n<512, k<256)
__global__ __launch_bounds__(256, 2)
void k_gemm1(const ushort_t* __restrict__ hid, const ushort_t* __restrict__ wcat,
             const float* __restrict__ b_in, const float* __restrict__ b_out,
             ushort_t* __restrict__ hcatT) {
  __shared__ __attribute__((aligned(16))) ushort_t lA[128*32];
  __shared__ __attribute__((aligned(16))) ushort_t lB[256*32];
  const int bb = blockIdx.y;
  const int j0 = (blockIdx.x >> 1) * 128;
  const int n0 = (blockIdx.x & 1) * 256;
  const int tid = threadIdx.x;
  const int w = tid >> 6, lane = tid & 63;
  const int ln = lane & 15, kg = lane >> 4;
  const int wm = w >> 1, wn = w & 1;
  const int lr = lane >> 2, lk = (lane & 3) * 8;

  f32x4 acc[4][8];
  #pragma unroll
  for (int i = 0; i < 4; ++i)
    #pragma unroll
    for (int j = 0; j < 8; ++j) acc[i][j] = (f32x4){0.f,0.f,0.f,0.f};

  const size_t arow0 = (size_t)bb * 512 + j0;
  for (int k0 = 0; k0 < 256; k0 += 32) {
    #pragma unroll
    for (int it = 0; it < 2; ++it) {
      int row = it*64 + w*16 + lr;
      cp16(hid + (arow0 + row)*256 + k0 + lk, lA + it*2048 + w*512);
    }
    #pragma unroll
    for (int it = 0; it < 4; ++it) {
      int row = it*64 + w*16 + lr;
      cp16(wcat + (size_t)(n0 + row)*256 + k0 + lk, lB + it*2048 + w*512);
    }
    __syncthreads();
    s16x8 af[4];
    #pragma unroll
    for (int mf = 0; mf < 4; ++mf)
      af[mf] = *(const s16x8*)&lA[(wm*64 + mf*16 + ln)*32 + kg*8];
    #pragma unroll
    for (int nf = 0; nf < 8; ++nf) {
      s16x8 bf = *(const s16x8*)&lB[(wn*128 + nf*16 + ln)*32 + kg*8];
      #pragma unroll
      for (int mf = 0; mf < 4; ++mf) acc[mf][nf] = mfma16(af[mf], bf, acc[mf][nf]);
    }
    __syncthreads();
  }
  #pragma unroll
  for (int nf = 0; nf < 8; ++nf) {
    int gn = n0 + wn*128 + nf*16 + ln;
    float bias = (gn < 256) ? b_in[gn] : b_out[gn - 256];
    #pragma unroll
    for (int mf = 0; mf < 4; ++mf) {
      int j = j0 + wm*64 + mf*16 + kg*4;
      u16x4 v;
      #pragma unroll
      for (int r = 0; r < 4; ++r) v[r] = f2h(acc[mf][nf][r] + bias);
      *(u16x4*)&hcatT[((size_t)(bb*512 + gn))*512 + j] = v;
    }
  }
}

// K2: inputs[b][i][h'] = sum_j A[b][i][half*512+j] * h_catT[b][h'][j] + bias(h')
__global__ __launch_bounds__(256, 2)
void k_gemm2(const float* __restrict__ A, const ushort_t* __restrict__ hcatT,
             const float* __restrict__ b_iah, const float* __restrict__ b_oah,
             ushort_t* __restrict__ inp) {
  __shared__ __attribute__((aligned(16))) ushort_t lA[128*40];   // padded (reg-staged)
  __shared__ __attribute__((aligned(16))) ushort_t lB[256*32];   // linear (cp16)
  const int bb = blockIdx.y;
  const int i0 = (blockIdx.x >> 1) * 128;
  const int half = blockIdx.x & 1;
  const int n0 = half * 256;
  const int tid = threadIdx.x;
  const int w = tid >> 6, lane = tid & 63;
  const int ln = lane & 15, kg = lane >> 4;
  const int wm = w >> 1, wn = w & 1;
  const int lr = lane >> 2, lk = (lane & 3) * 8;

  f32x4 acc[4][8];
  #pragma unroll
  for (int i = 0; i < 4; ++i)
    #pragma unroll
    for (int j = 0; j < 8; ++j) acc[i][j] = (f32x4){0.f,0.f,0.f,0.f};

  const float* Abase = A + ((size_t)bb*512 + i0)*1024 + half*512;
  for (int k0 = 0; k0 < 512; k0 += 32) {
    #pragma unroll
    for (int it = 0; it < 2; ++it) {
      int row = it*64 + (tid >> 2);
      const float* p = Abase + (size_t)row*1024 + k0 + (tid & 3)*8;
      f32x4 a0 = *(const f32x4*)p;
      f32x4 a1 = *(const f32x4*)(p + 4);
      s16x8 o;
      o[0]=(short)f2h(a0[0]); o[1]=(short)f2h(a0[1]); o[2]=(short)f2h(a0[2]); o[3]=(short)f2h(a0[3]);
      o[4]=(short)f2h(a1[0]); o[5]=(short)f2h(a1[1]); o[6]=(short)f2h(a1[2]); o[7]=(short)f2h(a1[3]);
      *(s16x8*)&lA[row*40 + (tid & 3)*8] = o;
    }
    #pragma unroll
    for (int it = 0; it < 4; ++it) {
      int row = it*64 + w*16 + lr;
      cp16(hcatT + ((size_t)(bb*512 + n0 + row))*512 + k0 + lk, lB + it*2048 + w*512);
    }
    __syncthreads();
    s16x8 af[4];
    #pragma unroll
    for (int mf = 0; mf < 4; ++mf)
      af[mf] = *(const s16x8*)&lA[(wm*64 + mf*16 + ln)*40 + kg*8];
    #pragma unroll
    for (int nf = 0; nf < 8; ++nf) {
      s16x8 bf = *(const s16x8*)&lB[(wn*128 + nf*16 + ln)*32 + kg*8];
      #pragma unroll
      for (int mf = 0; mf < 4; ++mf) acc[mf][nf] = mfma16(af[mf], bf, acc[mf][nf]);
    }
    __syncthreads();
  }
  #pragma unroll
  for (int nf = 0; nf < 8; ++nf) {
    int gn = n0 + wn*128 + nf*16 + ln;
    float bias = half ? b_oah[gn - 256] : b_iah[gn];
    #pragma unroll
    for (int mf = 0; mf < 4; ++mf) {
      #pragma unroll
      for (int r = 0; r < 4; ++r) {
        int i = i0 + wm*64 + mf*16 + kg*4 + r;
        inp[((size_t)(bb*512 + i))*512 + gn] = f2h(acc[mf][nf][r] + bias);
      }
    }
  }
}

// K3: fused gi (K=512) + gh (K=256) + GRU gates + residual -> out fp32
__global__ __launch_bounds__(256, 2)
void k_gemm3(const ushort_t* __restrict__ inp, const ushort_t* __restrict__ hidh,
             const ushort_t* __restrict__ wih, const ushort_t* __restrict__ whh,
             const float* __restrict__ b_ih, const float* __restrict__ b_hh,
             const float* __restrict__ hidden, float* __restrict__ out) {
  __shared__ __attribute__((aligned(16))) ushort_t lIn[128*32];
  __shared__ __attribute__((aligned(16))) ushort_t lW[192*32];
  const int m0 = blockIdx.y * 128;
  const int h0 = blockIdx.x * 64;
  const int tid = threadIdx.x;
  const int w = tid >> 6, lane = tid & 63;
  const int ln = lane & 15, kg = lane >> 4;
  const int lr = lane >> 2, lk = (lane & 3) * 8;

  f32x4 aR[2][4], aI[2][4], aIN[2][4], aHN[2][4];
  #pragma unroll
  for (int m = 0; m < 2; ++m)
    #pragma unroll
    for (int n = 0; n < 4; ++n) {
      aR[m][n] = (f32x4){0.f,0.f,0.f,0.f}; aI[m][n] = (f32x4){0.f,0.f,0.f,0.f};
      aIN[m][n] = (f32x4){0.f,0.f,0.f,0.f}; aHN[m][n] = (f32x4){0.f,0.f,0.f,0.f};
    }

  // phase 1: gi over inputs (K = 512)
  for (int k0 = 0; k0 < 512; k0 += 32) {
    #pragma unroll
    for (int it = 0; it < 2; ++it) {
      int row = it*64 + w*16 + lr;
      cp16(inp + (size_t)(m0 + row)*512 + k0 + lk, lIn + it*2048 + w*512);
    }
    #pragma unroll
    for (int it = 0; it < 3; ++it) {
      int rr = it*64 + w*16 + lr;
      int g = rr >> 6, r = rr & 63;
      cp16(wih + (size_t)(g*256 + h0 + r)*512 + k0 + lk, lW + it*2048 + w*512);
    }
    __syncthreads();
    s16x8 af[2];
    #pragma unroll
    for (int mf = 0; mf < 2; ++mf)
      af[mf] = *(const s16x8*)&lIn[(w*32 + mf*16 + ln)*32 + kg*8];
    #pragma unroll
    for (int g = 0; g < 3; ++g) {
      #pragma unroll
      for (int nf = 0; nf < 4; ++nf) {
        s16x8 bf = *(const s16x8*)&lW[(g*64 + nf*16 + ln)*32 + kg*8];
        #pragma unroll
        for (int mf = 0; mf < 2; ++mf) {
          f32x4& a = (g == 0 ? aR[mf][nf] : g == 1 ? aI[mf][nf] : aIN[mf][nf]);
          a = mfma16(af[mf], bf, a);
        }
      }
    }
    __syncthreads();
  }
  // phase 2: gh over hidden_h (K = 256)
  for (int k0 = 0; k0 < 256; k0 += 32) {
    #pragma unroll
    for (int it = 0; it < 2; ++it) {
      int row = it*64 + w*16 + lr;
      cp16(hidh + (size_t)(m0 + row)*256 + k0 + lk, lIn + it*2048 + w*512);
    }
    #pragma unroll
    for (int it = 0; it < 3; ++it) {
      int rr = it*64 + w*16 + lr;
      int g = rr >> 6, r = rr & 63;
      cp16(whh + (size_t)(g*256 + h0 + r)*256 + k0 + lk, lW + it*2048 + w*512);
    }
    __syncthreads();
    s16x8 af[2];
    #pragma unroll
    for (int mf = 0; mf < 2; ++mf)
      af[mf] = *(const s16x8*)&lIn[(w*32 + mf*16 + ln)*32 + kg*8];
    #pragma unroll
    for (int g = 0; g < 3; ++g) {
      #pragma unroll
      for (int nf = 0; nf < 4; ++nf) {
        s16x8 bf = *(const s16x8*)&lW[(g*64 + nf*16 + ln)*32 + kg*8];
        #pragma unroll
        for (int mf = 0; mf < 2; ++mf) {
          f32x4& a = (g == 0 ? aR[mf][nf] : g == 1 ? aI[mf][nf] : aHN[mf][nf]);
          a = mfma16(af[mf], bf, a);
        }
      }
    }
    __syncthreads();
  }
  // epilogue: gates + residual
  #pragma unroll
  for (int nf = 0; nf < 4; ++nf) {
    int h = h0 + nf*16 + ln;
    float br  = b_ih[h]       + b_hh[h];
    float bi  = b_ih[256 + h] + b_hh[256 + h];
    float bni = b_ih[512 + h];
    float bnh = b_hh[512 + h];
    #pragma unroll
    for (int mf = 0; mf < 2; ++mf) {
      #pragma unroll
      for (int r = 0; r < 4; ++r) {
        int m = m0 + w*32 + mf*16 + kg*4 + r;
        float rg = 1.0f / (1.0f + __expf(-(aR[mf][nf][r] + br)));
        float ig = 1.0f / (1.0f + __expf(-(aI[mf][nf][r] + bi)));
        float narg = aIN[mf][nf][r] + bni + rg * (aHN[mf][nf][r] + bnh);
        float e2 = __expf(2.0f * narg);
        float ng = 1.0f - 2.0f / (e2 + 1.0f);
        float hv = hidden[(size_t)m*256 + h];
        out[(size_t)m*256 + h] = hv + ig * (ng - hv);
      }
    }
  }
}

extern "C" void kernel_launch(void* const* d_in, const int* in_sizes, int n_in,
                              void* d_out, int out_size, void* d_ws, size_t ws_size,
                              hipStream_t stream) {
  const float* A      = (const float*)d_in[0];
  const float* hidden = (const float*)d_in[1];
  const float* W_in   = (const float*)d_in[3];
  const float* b_in   = (const float*)d_in[4];
  const float* W_out  = (const float*)d_in[5];
  const float* b_out  = (const float*)d_in[6];
  const float* b_iah  = (const float*)d_in[7];
  const float* b_oah  = (const float*)d_in[8];
  const float* w_ih   = (const float*)d_in[9];
  const float* b_ih   = (const float*)d_in[10];
  const float* w_hh   = (const float*)d_in[11];
  const float* b_hh   = (const float*)d_in[12];
  float* out = (float*)d_out;

  char* ws = (char*)d_ws;
  ushort_t* hidh  = (ushort_t*)(ws);                 // 32 MB
  ushort_t* wcat  = (ushort_t*)(ws + 33554432);      // 256 KB
  ushort_t* wihh  = (ushort_t*)(ws + 33816576);      // 768 KB
  ushort_t* whhh  = (ushort_t*)(ws + 34603008);      // 384 KB
  ushort_t* hcatT = (ushort_t*)(ws + 34996224);      // 64 MB
  ushort_t* inp   = (ushort_t*)(ws + 102105088);     // 64 MB  (total ~161.4 MB)

  k_cvt_f16<<<8192, 256, 0, stream>>>(hidden, hidh, M_*H_/8);
  k_cvt_f16<<<32,   256, 0, stream>>>(W_in,  wcat,           H_*H_/8);
  k_cvt_f16<<<32,   256, 0, stream>>>(W_out, wcat + H_*H_,   H_*H_/8);
  k_cvt_f16<<<192,  256, 0, stream>>>(w_ih,  wihh, 768*512/8);
  k_cvt_f16<<<96,   256, 0, stream>>>(w_hh,  whhh, 768*256/8);

  k_gemm1<<<dim3(8, 128), 256, 0, stream>>>(hidh, wcat, b_in, b_out, hcatT);
  k_gemm2<<<dim3(8, 128), 256, 0, stream>>>(A, hcatT, b_iah, b_oah, inp);
  k_gemm3<<<dim3(4, 512), 256, 0, stream>>>(inp, hidh, wihh, whhh, b_ih, b_hh, hidden, out);
}